// Round 8
// baseline (150.099 us; speedup 1.0000x reference)
//
#include <hip/hip_runtime.h>

#define D 64
#define NPB 128              // nodes per bucket (dstLocal: 7 bits)
#define NPB_SHIFT 7
#define MAXB 1024            // bound on bucket count B = ceil(N/NPB)
#define SCATTER_T 512
#define CHUNK_MAX 2352       // max edges staged per scatter block (2 blocks/CU)
#define SCQ 5                // per-thread reg-staged edges (SCQ*512 >= CHUNK_MAX)
#define CAPB 2560            // fixed per-bucket capacity in adjB (mean 1534)
#define GT 512               // sort_gather block size (8 waves)
#define GQ 5                 // per-thread reg-staged bucket entries (GQ*GT >= CAPB)

// round-to-nearest-even fp32 -> bf16 (values are finite/normal here)
__device__ inline unsigned f2bf(float f) {
    unsigned u = __float_as_uint(f);
    return (u + 0x7FFFu + ((u >> 16) & 1u)) >> 16;
}

// ---------------------------------------------------------------------------
// zero helper (fallback path only)
// ---------------------------------------------------------------------------
__global__ void zero_f4_kernel(float4* __restrict__ p, int n4) {
    int i = blockIdx.x * blockDim.x + threadIdx.x;
    if (i < n4) p[i] = make_float4(0.f, 0.f, 0.f, 0.f);
}

// ---------------------------------------------------------------------------
// bucket scatter v4: 2 blocks/CU (511 blocks; r7 ran 1/CU = 8 waves with a
// barrier-phased pipeline and nothing to hide latency behind) and the 18-
// barrier Hillis-Steele scan replaced by shfl wave-scan + 8-entry combine
// (4 barriers total). Otherwise r5-proven structure: reg-stage edges ->
// LDS chunk histogram -> local excl scan -> reserve per-bucket ranges ->
// LDS counting sort -> coalesced write-out. Overflow past CAPB -> ovf.
// Packing: x = src | dstLocal<<20, y = w bits.
// ---------------------------------------------------------------------------
__global__ __launch_bounds__(SCATTER_T) void bucket_scatter_kernel(
        const int* __restrict__ src, const int* __restrict__ dst,
        const float* __restrict__ w, int* __restrict__ cursor,
        int* __restrict__ ovfCnt, int4* __restrict__ ovf,
        int2* __restrict__ adjB, int E, int B) {
    __shared__ int lc[MAXB];
    __shared__ int lpre[MAXB];
    __shared__ int lbase[MAXB];
    __shared__ int lfill[MAXB];
    __shared__ int wsum[8];
    __shared__ int wexc[8];
    __shared__ unsigned short sb[CHUNK_MAX];
    __shared__ int2 stage[CHUNK_MAX];

    int t = threadIdx.x;
    int chunk = (E + gridDim.x - 1) / gridDim.x;   // <= CHUNK_MAX by host calc
    int lo = blockIdx.x * chunk, hi = min(lo + chunk, E);
    int n = hi - lo;
    if (n <= 0) return;

    for (int i = t; i < MAXB; i += SCATTER_T) { lc[i] = 0; lfill[i] = 0; }

    // reg-stage this thread's edges (one global pass over dst/src/w)
    int rd[SCQ]; int rs[SCQ]; float rw[SCQ];
#pragma unroll
    for (int q = 0; q < SCQ; ++q) {
        int e = lo + t + q * SCATTER_T;
        bool v = e < hi;
        rd[q] = v ? dst[e] : -1;
        rs[q] = v ? src[e] : 0;
        rw[q] = v ? w[e] : 0.f;
    }
    __syncthreads();

    // A1: chunk histogram
#pragma unroll
    for (int q = 0; q < SCQ; ++q)
        if (rd[q] >= 0) atomicAdd(&lc[rd[q] >> NPB_SHIFT], 1);
    __syncthreads();

    // A2: exclusive scan of lc[0..MAXB): 2 counts/thread, shfl wave-scan
    // (no barriers) + 8 wave totals combined by threads 0..7. 2 barriers.
    int s0 = lc[2 * t], s1 = lc[2 * t + 1];
    int tsum = s0 + s1;
    int lane = t & 63, wid = t >> 6;
    int v = tsum;
#pragma unroll
    for (int off = 1; off < 64; off <<= 1) {
        int u = __shfl_up(v, off, 64);
        if (lane >= off) v += u;
    }
    if (lane == 63) wsum[wid] = v;          // wave total (inclusive of all 64)
    __syncthreads();
    if (t < 8) {
        int acc = 0;
        for (int i = 0; i < t; ++i) acc += wsum[i];
        wexc[t] = acc;                       // exclusive wave base
    }
    __syncthreads();
    int base = wexc[wid] + (v - tsum);       // exclusive prefix for this thread
    lpre[2 * t] = base;
    lpre[2 * t + 1] = base + s0;
    __syncthreads();

    // A3: reserve per-bucket ranges (1 global atomic per nonempty bucket)
    for (int i = t; i < B; i += SCATTER_T) {
        int c = lc[i];
        lbase[i] = c ? atomicAdd(&cursor[i], c) : 0;
    }
    __syncthreads();

    // B: place into locally-sorted LDS slots
#pragma unroll
    for (int q = 0; q < SCQ; ++q) {
        int d = rd[q];
        if (d >= 0) {
            int bkt = d >> NPB_SHIFT;
            int i = lpre[bkt] + atomicAdd(&lfill[bkt], 1);
            stage[i] = make_int2(rs[q] | ((d & (NPB - 1)) << 20),
                                 __float_as_int(rw[q]));
            sb[i] = (unsigned short)bkt;
        }
    }
    __syncthreads();

    // C: coalesced write-out in locally-sorted order
    for (int i = t; i < n; i += SCATTER_T) {
        int bkt = sb[i];
        int2 vv = stage[i];
        int pos = lbase[bkt] + (i - lpre[bkt]);
        if (pos < CAPB) {
            adjB[(size_t)bkt * CAPB + pos] = vv;
        } else {                               // cold: bucket overflow
            int oi = atomicAdd(ovfCnt, 1);
            ovf[oi] = make_int4(vv.x, vv.y, bkt, 0);
        }
    }
}

// ---------------------------------------------------------------------------
// fused sort+gather (r3/r7-proven): one block per bucket. Single global pass
// stages the bucket's adjB slice into registers while counting; after the
// scan each thread places its staged entries node-grouped into LDS. Gather:
// each HALF-WAVE owns a node, now with 8-deep proj-load pipeline (mean
// degree ~12 -> one 8-batch + remainder instead of 3 serial 4-batches).
// REGISTER accumulation — r5/r6 lesson: streaming LDS-atomic accumulate is
// ~10x slower regardless of atomic flavor. Overflow drained with global
// float atomics after the block's own stores.
// ---------------------------------------------------------------------------
__global__ __launch_bounds__(GT) void sort_gather_kernel(
        const int2* __restrict__ adjB, const int* __restrict__ cursor,
        const int* __restrict__ ovfCnt, const int4* __restrict__ ovf,
        const unsigned* __restrict__ projU, float* __restrict__ out, int N) {
    __shared__ int cnt[NPB];
    __shared__ int pre[NPB];
    __shared__ int fill[NPB];
    __shared__ int2 ladj[CAPB];
    __shared__ int sOvf;

    int b = blockIdx.x;
    int t = threadIdx.x;
    int total = cursor[b];
    int m = min(total, CAPB);
    const int2* base = adjB + (size_t)b * CAPB;

    if (t < NPB) { cnt[t] = 0; fill[t] = 0; }
    if (t == 0) sOvf = *ovfCnt;
    __syncthreads();

    // single global pass: reg-stage + histogram
    int2 r[GQ];
#pragma unroll
    for (int q = 0; q < GQ; ++q) {
        int e = t + q * GT;
        if (e < m) {
            int2 a = base[e];
            r[q] = a;
            atomicAdd(&cnt[((unsigned)a.x) >> 20], 1);
        }
    }
    __syncthreads();
    if (t < NPB) pre[t] = cnt[t];
    __syncthreads();
    for (int st = 1; st < NPB; st <<= 1) {
        int v = (t < NPB && t >= st) ? pre[t - st] : 0;
        __syncthreads();
        if (t < NPB) pre[t] += v;
        __syncthreads();
    }
    // place node-grouped into LDS from registers
#pragma unroll
    for (int q = 0; q < GQ; ++q) {
        int e = t + q * GT;
        if (e < m) {
            int2 a = r[q];
            int dL = ((unsigned)a.x) >> 20;
            int pos = ((dL == 0) ? 0 : pre[dL - 1]) + atomicAdd(&fill[dL], 1);
            ladj[pos] = make_int2(a.x & 0xFFFFF, a.y);
        }
    }
    __syncthreads();

    int wave = t >> 6;          // 0..7
    int lane = t & 63;
    int half = lane >> 5;
    int k = lane & 31;          // lane owns dims {2k, 2k+1} of its half's node

#pragma unroll 1
    for (int i = 0; i < 8; ++i) {            // 2 nodes per wave-iter
        int dL = wave * 16 + i * 2 + half;
        int node = b * NPB + dL;
        if (node < N) {
            int rb = (dL == 0) ? 0 : pre[dL - 1];
            int re = pre[dL];
            float2 accA = make_float2(0.f, 0.f);
            float2 accB = make_float2(0.f, 0.f);
            int j = rb;
            for (; j + 7 < re; j += 8) {     // 8 proj loads in flight per half
                int2 a0 = ladj[j];
                int2 a1 = ladj[j + 1];
                int2 a2 = ladj[j + 2];
                int2 a3 = ladj[j + 3];
                int2 a4 = ladj[j + 4];
                int2 a5 = ladj[j + 5];
                int2 a6 = ladj[j + 6];
                int2 a7 = ladj[j + 7];
                unsigned p0 = projU[(size_t)a0.x * 32 + k];
                unsigned p1 = projU[(size_t)a1.x * 32 + k];
                unsigned p2 = projU[(size_t)a2.x * 32 + k];
                unsigned p3 = projU[(size_t)a3.x * 32 + k];
                unsigned p4 = projU[(size_t)a4.x * 32 + k];
                unsigned p5 = projU[(size_t)a5.x * 32 + k];
                unsigned p6 = projU[(size_t)a6.x * 32 + k];
                unsigned p7 = projU[(size_t)a7.x * 32 + k];
                float w0 = __int_as_float(a0.y), w1 = __int_as_float(a1.y);
                float w2 = __int_as_float(a2.y), w3 = __int_as_float(a3.y);
                float w4 = __int_as_float(a4.y), w5 = __int_as_float(a5.y);
                float w6 = __int_as_float(a6.y), w7 = __int_as_float(a7.y);
                accA.x += w0 * __uint_as_float(p0 << 16);
                accA.y += w0 * __uint_as_float(p0 & 0xFFFF0000u);
                accB.x += w1 * __uint_as_float(p1 << 16);
                accB.y += w1 * __uint_as_float(p1 & 0xFFFF0000u);
                accA.x += w2 * __uint_as_float(p2 << 16);
                accA.y += w2 * __uint_as_float(p2 & 0xFFFF0000u);
                accB.x += w3 * __uint_as_float(p3 << 16);
                accB.y += w3 * __uint_as_float(p3 & 0xFFFF0000u);
                accA.x += w4 * __uint_as_float(p4 << 16);
                accA.y += w4 * __uint_as_float(p4 & 0xFFFF0000u);
                accB.x += w5 * __uint_as_float(p5 << 16);
                accB.y += w5 * __uint_as_float(p5 & 0xFFFF0000u);
                accA.x += w6 * __uint_as_float(p6 << 16);
                accA.y += w6 * __uint_as_float(p6 & 0xFFFF0000u);
                accB.x += w7 * __uint_as_float(p7 << 16);
                accB.y += w7 * __uint_as_float(p7 & 0xFFFF0000u);
            }
            for (; j + 3 < re; j += 4) {     // 4-deep remainder
                int2 a0 = ladj[j];
                int2 a1 = ladj[j + 1];
                int2 a2 = ladj[j + 2];
                int2 a3 = ladj[j + 3];
                unsigned p0 = projU[(size_t)a0.x * 32 + k];
                unsigned p1 = projU[(size_t)a1.x * 32 + k];
                unsigned p2 = projU[(size_t)a2.x * 32 + k];
                unsigned p3 = projU[(size_t)a3.x * 32 + k];
                float w0 = __int_as_float(a0.y), w1 = __int_as_float(a1.y);
                float w2 = __int_as_float(a2.y), w3 = __int_as_float(a3.y);
                accA.x += w0 * __uint_as_float(p0 << 16);
                accA.y += w0 * __uint_as_float(p0 & 0xFFFF0000u);
                accB.x += w1 * __uint_as_float(p1 << 16);
                accB.y += w1 * __uint_as_float(p1 & 0xFFFF0000u);
                accA.x += w2 * __uint_as_float(p2 << 16);
                accA.y += w2 * __uint_as_float(p2 & 0xFFFF0000u);
                accB.x += w3 * __uint_as_float(p3 << 16);
                accB.y += w3 * __uint_as_float(p3 & 0xFFFF0000u);
            }
            for (; j < re; ++j) {
                int2 a0 = ladj[j];
                float w0 = __int_as_float(a0.y);
                unsigned p0 = projU[(size_t)a0.x * 32 + k];
                accA.x += w0 * __uint_as_float(p0 << 16);
                accA.y += w0 * __uint_as_float(p0 & 0xFFFF0000u);
            }
            float2 acc = make_float2(accA.x + accB.x, accA.y + accB.y);
            *(float2*)&out[(size_t)node * D + 2 * k] = acc;  // 32 lanes x 8B
        }
    }

    if (sOvf > 0) {                           // insurance path, never hot
        __syncthreads();                      // order our stores before atomics
        for (int e = t; e < sOvf; e += GT) {
            int4 o = ovf[e];
            if (o.z != b) continue;
            int dL = ((unsigned)o.x) >> 20;
            int node = b * NPB + dL;
            if (node >= N) continue;
            float wgt = __int_as_float(o.y);
            int s = o.x & 0xFFFFF;
            for (int d2 = 0; d2 < D / 2; ++d2) {
                unsigned p = projU[(size_t)s * 32 + d2];
                atomicAdd(&out[(size_t)node * D + 2 * d2],     wgt * __uint_as_float(p << 16));
                atomicAdd(&out[(size_t)node * D + 2 * d2 + 1], wgt * __uint_as_float(p & 0xFFFF0000u));
            }
        }
    }
}

// ---------------------------------------------------------------------------
// Tiled row GEMM -> bf16 packed proj (r2-proven, adjacent-pair words).
// Launched FIRST; block 0 also zeroes cursor[B] + ovfCnt (replaces the
// zero_i dispatch — scatter runs after this kernel in stream order).
// Block = 64 rows; A staged transposed in LDS; theta in LDS; 4x4/thread.
// __launch_bounds__(256,4): cap VGPR at 128. unroll 16 keeps ILP in cap.
// ---------------------------------------------------------------------------
__global__ __launch_bounds__(256, 4) void rowgemm_bf16_kernel(const float* __restrict__ A,
                                                              const float* __restrict__ theta,
                                                              unsigned short* __restrict__ proj16,
                                                              int* __restrict__ cursor,
                                                              int nCur, int N) {
    __shared__ float th[D * D];
    __shared__ float at[D][68];
    int t = threadIdx.x;
    int rowBase = blockIdx.x * 64;

    if (blockIdx.x == 0)                          // fold cursor zeroing here
        for (int i = t; i < nCur; i += 256) cursor[i] = 0;

#pragma unroll
    for (int i = 0; i < 4; ++i) {
        int f = t + i * 256;
        ((float4*)th)[f] = ((const float4*)theta)[f];
    }
#pragma unroll
    for (int i = 0; i < 4; ++i) {
        int f = t + i * 256;
        int row = f >> 4;
        int kv = f & 15;
        float4 v = make_float4(0.f, 0.f, 0.f, 0.f);
        if (rowBase + row < N) v = *(const float4*)&A[(size_t)(rowBase + row) * D + kv * 4];
        at[kv * 4 + 0][row] = v.x;
        at[kv * 4 + 1][row] = v.y;
        at[kv * 4 + 2][row] = v.z;
        at[kv * 4 + 3][row] = v.w;
    }
    __syncthreads();

    int c0 = (t & 15) * 4;
    int r0 = (t >> 4) * 4;
    float4 acc0 = make_float4(0.f, 0.f, 0.f, 0.f);
    float4 acc1 = acc0, acc2 = acc0, acc3 = acc0;

#pragma unroll 16
    for (int k = 0; k < D; ++k) {
        float4 bv = *(const float4*)&th[k * D + c0];
        float4 av = *(const float4*)&at[k][r0];
        acc0.x += av.x * bv.x; acc0.y += av.x * bv.y; acc0.z += av.x * bv.z; acc0.w += av.x * bv.w;
        acc1.x += av.y * bv.x; acc1.y += av.y * bv.y; acc1.z += av.y * bv.z; acc1.w += av.y * bv.w;
        acc2.x += av.z * bv.x; acc2.y += av.z * bv.y; acc2.z += av.z * bv.z; acc2.w += av.z * bv.w;
        acc3.x += av.w * bv.x; acc3.y += av.w * bv.y; acc3.z += av.w * bv.z; acc3.w += av.w * bv.w;
    }

    float4 accs[4] = {acc0, acc1, acc2, acc3};
#pragma unroll
    for (int i = 0; i < 4; ++i) {
        int r = rowBase + r0 + i;
        if (r < N) {
            unsigned lo = f2bf(accs[i].x) | (f2bf(accs[i].y) << 16);
            unsigned hi = f2bf(accs[i].z) | (f2bf(accs[i].w) << 16);
            *(uint2*)&proj16[(size_t)r * D + c0] = make_uint2(lo, hi);
        }
    }
}

// ---------------------------------------------------------------------------
// fallback path (atomic scatter + fp32 row GEMM) if ws/shape checks fail
// ---------------------------------------------------------------------------
__global__ void scatter_kernel(const int* __restrict__ src, const int* __restrict__ dst,
                               const float* __restrict__ w, const float* __restrict__ data,
                               float* __restrict__ agg, int E) {
    int tid = blockIdx.x * blockDim.x + threadIdx.x;
    int e = tid >> 6;
    int d = tid & 63;
    if (e >= E) return;
    float val = w[e] * data[(size_t)src[e] * D + d];
    atomicAdd(&agg[(size_t)dst[e] * D + d], val);
}

__global__ __launch_bounds__(256, 4) void rowgemm_f32_kernel(const float* __restrict__ A,
                                                             const float* __restrict__ theta,
                                                             float* __restrict__ out, int N) {
    __shared__ float th[D * D];
    __shared__ float at[D][68];
    int t = threadIdx.x;
    int rowBase = blockIdx.x * 64;
#pragma unroll
    for (int i = 0; i < 4; ++i) {
        int f = t + i * 256;
        ((float4*)th)[f] = ((const float4*)theta)[f];
    }
#pragma unroll
    for (int i = 0; i < 4; ++i) {
        int f = t + i * 256;
        int row = f >> 4;
        int kv = f & 15;
        float4 v = make_float4(0.f, 0.f, 0.f, 0.f);
        if (rowBase + row < N) v = *(const float4*)&A[(size_t)(rowBase + row) * D + kv * 4];
        at[kv * 4 + 0][row] = v.x;
        at[kv * 4 + 1][row] = v.y;
        at[kv * 4 + 2][row] = v.z;
        at[kv * 4 + 3][row] = v.w;
    }
    __syncthreads();
    int c0 = (t & 15) * 4;
    int r0 = (t >> 4) * 4;
    float4 acc0 = make_float4(0.f, 0.f, 0.f, 0.f);
    float4 acc1 = acc0, acc2 = acc0, acc3 = acc0;
#pragma unroll 16
    for (int kk = 0; kk < D; ++kk) {
        float4 bv = *(const float4*)&th[kk * D + c0];
        float4 av = *(const float4*)&at[kk][r0];
        acc0.x += av.x * bv.x; acc0.y += av.x * bv.y; acc0.z += av.x * bv.z; acc0.w += av.x * bv.w;
        acc1.x += av.y * bv.x; acc1.y += av.y * bv.y; acc1.z += av.y * bv.z; acc1.w += av.y * bv.w;
        acc2.x += av.z * bv.x; acc2.y += av.z * bv.y; acc2.z += av.z * bv.z; acc2.w += av.z * bv.w;
        acc3.x += av.w * bv.x; acc3.y += av.w * bv.y; acc3.z += av.w * bv.z; acc3.w += av.w * bv.w;
    }
    float4 accs[4] = {acc0, acc1, acc2, acc3};
#pragma unroll
    for (int i = 0; i < 4; ++i) {
        int r = rowBase + r0 + i;
        if (r < N) *(float4*)&out[(size_t)r * D + c0] = accs[i];
    }
}

extern "C" void kernel_launch(void* const* d_in, const int* in_sizes, int n_in,
                              void* d_out, int out_size, void* d_ws, size_t ws_size,
                              hipStream_t stream) {
    const int*   src   = (const int*)d_in[0];
    const int*   dst   = (const int*)d_in[1];
    const float* w     = (const float*)d_in[2];
    const float* data  = (const float*)d_in[3];
    const float* theta = (const float*)d_in[4];
    const int E = in_sizes[0];
    const int N = in_sizes[3] / D;
    float* out = (float*)d_out;

    const int B = (N + NPB - 1) / NPB;

    // ws layout: proj16 (bf16, adjacent-pair words) | adjB (B*CAPB int2) |
    //            ovf (E int4) | cursor[B] | ovfCnt
    size_t projBytes = (size_t)N * D * 2;
    size_t adjBytes  = (size_t)B * CAPB * 8;
    size_t ovfBytes  = (size_t)E * 16;
    size_t need = projBytes + adjBytes + ovfBytes + ((size_t)B + 1) * 4 + 256;

    if (ws_size >= need && N < (1 << 20) && B <= MAXB) {
        unsigned short* proj16 = (unsigned short*)d_ws;
        int2* adjB   = (int2*)((char*)d_ws + projBytes);
        int4* ovf    = (int4*)((char*)d_ws + projBytes + adjBytes);
        int*  cursor = (int*)((char*)d_ws + projBytes + adjBytes + ovfBytes);
        int*  ovfCnt = cursor + B;

        int gs = (E + CHUNK_MAX - 1) / CHUNK_MAX;  // chunk <= CHUNK_MAX

        rowgemm_bf16_kernel<<<(N + 63) / 64, 256, 0, stream>>>(data, theta, proj16,
                                                               cursor, B + 1, N);
        bucket_scatter_kernel<<<gs, SCATTER_T, 0, stream>>>(src, dst, w, cursor,
                                                            ovfCnt, ovf, adjB, E, B);
        sort_gather_kernel<<<B, GT, 0, stream>>>(adjB, cursor, ovfCnt, ovf,
                                                 (const unsigned*)proj16, out, N);
    } else {
        float* agg = (float*)d_ws;
        int n4 = (N * D) / 4;
        zero_f4_kernel<<<(n4 + 255) / 256, 256, 0, stream>>>((float4*)agg, n4);
        long long total = (long long)E * D;
        scatter_kernel<<<(int)((total + 255) / 256), 256, 0, stream>>>(src, dst, w, data, agg, E);
        rowgemm_f32_kernel<<<(N + 63) / 64, 256, 0, stream>>>(agg, theta, out, N);
    }
}